// Round 1
// baseline (4356.887 us; speedup 1.0000x reference)
//
#include <hip/hip_runtime.h>

// Bahdanau attention: B=32, T=512, S=1024, H=512, fp32.
// out = context [B,T,H] ++ attn_last [B,S]
// ws  = Wsq [B,T,H] (33.5MB) ++ Whe [B,S,H] (67MB)  -> needs ~96MB workspace.

constexpr int B = 32, T = 512, S = 1024, H = 512;
constexpr int TT = 8;    // timesteps per attn block
constexpr int SS = 32;   // staged Whe rows per tile

#define DEVI __device__ __forceinline__

DEVI float fast_tanh(float x) {
  // tanh(x) = 1 - 2/(exp(2x)+1); exp(2x) = exp2(x * 2*log2(e))
  float e = __builtin_amdgcn_exp2f(x * 2.88539008177792681f);
  return __builtin_fmaf(-2.0f, __builtin_amdgcn_rcpf(e + 1.0f), 1.0f);
}

// C[M][512] = A[M][512] * W[512][512]^T   (C[m][o] = sum_h A[m][h]*W[o][h])
__global__ __launch_bounds__(256)
void matmul_nt_kernel(const float* __restrict__ A, const float* __restrict__ W,
                      float* __restrict__ C) {
  constexpr int K = H, N = H, BM = 64, BN = 64, BK = 16;
  __shared__ __align__(16) float As[BK][BM + 4];
  __shared__ __align__(16) float Bs[BK][BN + 4];
  const int nbx = N / BN;  // 8
  const int bx = blockIdx.x % nbx, by = blockIdx.x / nbx;
  const int tid = threadIdx.x;
  const int tx = tid & 15, ty = tid >> 4;
  const int row0 = by * BM, col0 = bx * BN;
  const int lr = tid >> 2, lk = (tid & 3) * 4;
  float acc[4][4] = {};
  for (int k0 = 0; k0 < K; k0 += BK) {
    // prefetch to regs while LDS still in use by previous iter's compute
    float4 av = *(const float4*)&A[(size_t)(row0 + lr) * K + k0 + lk];
    float4 wv = *(const float4*)&W[(size_t)(col0 + lr) * K + k0 + lk];
    __syncthreads();
    As[lk + 0][lr] = av.x; As[lk + 1][lr] = av.y; As[lk + 2][lr] = av.z; As[lk + 3][lr] = av.w;
    Bs[lk + 0][lr] = wv.x; Bs[lk + 1][lr] = wv.y; Bs[lk + 2][lr] = wv.z; Bs[lk + 3][lr] = wv.w;
    __syncthreads();
#pragma unroll
    for (int k = 0; k < BK; ++k) {
      float4 a4 = *(const float4*)&As[k][ty * 4];
      float4 w4 = *(const float4*)&Bs[k][tx * 4];
      float a[4] = {a4.x, a4.y, a4.z, a4.w};
      float w[4] = {w4.x, w4.y, w4.z, w4.w};
#pragma unroll
      for (int i = 0; i < 4; ++i)
#pragma unroll
        for (int j = 0; j < 4; ++j) acc[i][j] = __builtin_fmaf(a[i], w[j], acc[i][j]);
    }
  }
#pragma unroll
  for (int i = 0; i < 4; ++i) {
    float4 o = make_float4(acc[i][0], acc[i][1], acc[i][2], acc[i][3]);
    *(float4*)&C[(size_t)(row0 + ty * 4 + i) * N + col0 + tx * 4] = o;
  }
}

// Fused: scores (tanh) -> masked softmax -> context. One block = (b, 8 timesteps).
__global__ __launch_bounds__(256, 1)
void attn_fused_kernel(const float* __restrict__ wsq, const float* __restrict__ whe,
                       const float* __restrict__ enc, const float* __restrict__ v,
                       const int* __restrict__ lens, float* __restrict__ out) {
  __shared__ __align__(16) float s_wsq[TT][H + 4];   // 16.5 KB
  __shared__ __align__(16) float s_whe[SS][H + 4];   // 66 KB
  __shared__ __align__(16) float s_v[H];             // 2 KB
  __shared__ __align__(16) float s_sc[TT][S];        // 32 KB: scores, then p (in place)
  __shared__ float s_rs[TT];                          // 1/sum per row

  const int b = blockIdx.x & (B - 1);        // blockIdx%8 = b%8 -> batch pinned to one XCD
  const int tt = blockIdx.x / B;             // 0..63
  const int tid = threadIdx.x;
  const int len = lens[b];

  // load Wsq rows for this t-tile + v
  {
    int r = tid >> 5;            // 0..7
    int c0 = (tid & 31) * 4;     // 0..124
#pragma unroll
    for (int u = 0; u < 4; ++u) {
      int c = c0 + u * 128;
      *(float4*)&s_wsq[r][c] = *(const float4*)&wsq[((size_t)b * T + tt * TT + r) * H + c];
    }
    if (tid < H / 4) *(float4*)&s_v[tid * 4] = *(const float4*)&v[tid * 4];
  }

  const int t = tid >> 5;      // 0..7
  const int srow = tid & 31;   // 0..31

  // ---- Phase A: scores ----
  for (int st = 0; st < S / SS; ++st) {
    __syncthreads();
    {
      int r = tid >> 3;          // 0..31
      int c0 = (tid & 7) * 4;    // 0..28
#pragma unroll
      for (int u = 0; u < 16; ++u) {
        int c = c0 + u * 32;
        *(float4*)&s_whe[r][c] = *(const float4*)&whe[((size_t)b * S + st * SS + r) * H + c];
      }
    }
    __syncthreads();
    float a0 = 0.f, a1 = 0.f, a2 = 0.f, a3 = 0.f;
    const float* qp = &s_wsq[t][0];
    const float* ep = &s_whe[srow][0];
#pragma unroll 4
    for (int h = 0; h < H; h += 8) {
      float4 q0 = *(const float4*)(qp + h), q1 = *(const float4*)(qp + h + 4);
      float4 e0 = *(const float4*)(ep + h), e1 = *(const float4*)(ep + h + 4);
      float4 v0 = *(const float4*)(&s_v[h]), v1 = *(const float4*)(&s_v[h + 4]);
      a0 = __builtin_fmaf(v0.x, fast_tanh(q0.x + e0.x), a0);
      a1 = __builtin_fmaf(v0.y, fast_tanh(q0.y + e0.y), a1);
      a2 = __builtin_fmaf(v0.z, fast_tanh(q0.z + e0.z), a2);
      a3 = __builtin_fmaf(v0.w, fast_tanh(q0.w + e0.w), a3);
      a0 = __builtin_fmaf(v1.x, fast_tanh(q1.x + e1.x), a0);
      a1 = __builtin_fmaf(v1.y, fast_tanh(q1.y + e1.y), a1);
      a2 = __builtin_fmaf(v1.z, fast_tanh(q1.z + e1.z), a2);
      a3 = __builtin_fmaf(v1.w, fast_tanh(q1.w + e1.w), a3);
    }
    s_sc[t][st * SS + srow] = (a0 + a1) + (a2 + a3);
  }
  __syncthreads();

  // ---- Phase B: masked softmax per row; wave w handles rows 2w, 2w+1 ----
  {
    const int wv = tid >> 6, lane = tid & 63;
#pragma unroll
    for (int j = 0; j < 2; ++j) {
      const int tr = wv * 2 + j;
      float vals[S / 64], ps[S / 64];
      float m = -3.0e38f;
#pragma unroll
      for (int i = 0; i < S / 64; ++i) {
        int s = lane + 64 * i;
        vals[i] = s_sc[tr][s];
        if (s < len) m = fmaxf(m, vals[i]);
      }
#pragma unroll
      for (int o = 1; o < 64; o <<= 1) m = fmaxf(m, __shfl_xor(m, o, 64));
      float sum = 0.f;
#pragma unroll
      for (int i = 0; i < S / 64; ++i) {
        int s = lane + 64 * i;
        float p = (s < len) ? __builtin_amdgcn_exp2f((vals[i] - m) * 1.44269504088896341f) : 0.f;
        ps[i] = p;
        sum += p;
      }
#pragma unroll
      for (int o = 1; o < 64; o <<= 1) sum += __shfl_xor(sum, o, 64);
      float rs = 1.0f / sum;
#pragma unroll
      for (int i = 0; i < S / 64; ++i) s_sc[tr][lane + 64 * i] = ps[i];
      if (lane == 0) s_rs[tr] = rs;
      if (tt == T / TT - 1 && tr == TT - 1) {  // last timestep: emit attention weights
#pragma unroll
        for (int i = 0; i < S / 64; ++i)
          out[(size_t)B * T * H + (size_t)b * S + lane + 64 * i] = ps[i] * rs;
      }
    }
  }
  __syncthreads();

  // ---- Phase C: ctx[t][h] = sum_s p[t][s] * enc[b][s][h] ----
  {
    const int tg = tid >> 6, lane = tid & 63;   // t in {tg, tg+4}
    const int h0 = lane * 4, h1 = 256 + lane * 4;
    float acc0[8] = {}, acc1[8] = {};
#pragma unroll 2
    for (int s = 0; s < S; ++s) {
      float p0 = s_sc[tg][s];
      float p1 = s_sc[tg + 4][s];
      const float* er = enc + ((size_t)b * S + s) * H;
      float4 e0 = *(const float4*)(er + h0);
      float4 e1 = *(const float4*)(er + h1);
      float ev[8] = {e0.x, e0.y, e0.z, e0.w, e1.x, e1.y, e1.z, e1.w};
#pragma unroll
      for (int k = 0; k < 8; ++k) {
        acc0[k] = __builtin_fmaf(p0, ev[k], acc0[k]);
        acc1[k] = __builtin_fmaf(p1, ev[k], acc1[k]);
      }
    }
    const float rs0 = s_rs[tg], rs1 = s_rs[tg + 4];
    const size_t base0 = ((size_t)b * T + tt * TT + tg) * H;
    const size_t base1 = ((size_t)b * T + tt * TT + tg + 4) * H;
    float4 o;
    o = make_float4(acc0[0] * rs0, acc0[1] * rs0, acc0[2] * rs0, acc0[3] * rs0);
    *(float4*)&out[base0 + h0] = o;
    o = make_float4(acc0[4] * rs0, acc0[5] * rs0, acc0[6] * rs0, acc0[7] * rs0);
    *(float4*)&out[base0 + h1] = o;
    o = make_float4(acc1[0] * rs1, acc1[1] * rs1, acc1[2] * rs1, acc1[3] * rs1);
    *(float4*)&out[base1 + h0] = o;
    o = make_float4(acc1[4] * rs1, acc1[5] * rs1, acc1[6] * rs1, acc1[7] * rs1);
    *(float4*)&out[base1 + h1] = o;
  }
}

extern "C" void kernel_launch(void* const* d_in, const int* in_sizes, int n_in,
                              void* d_out, int out_size, void* d_ws, size_t ws_size,
                              hipStream_t stream) {
  const float* query = (const float*)d_in[0];  // [B,T,H]
  const float* enc   = (const float*)d_in[1];  // [B,S,H]
  const int*   lens  = (const int*)d_in[2];    // [B]
  const float* Ws    = (const float*)d_in[3];  // [H,H]
  const float* Wh    = (const float*)d_in[4];  // [H,H]
  const float* v     = (const float*)d_in[5];  // [H]
  float* out = (float*)d_out;
  float* wsq = (float*)d_ws;                   // [B,T,H]
  float* whe = wsq + (size_t)B * T * H;        // [B,S,H]

  matmul_nt_kernel<<<dim3((B * T / 64) * 8), 256, 0, stream>>>(query, Ws, wsq);
  matmul_nt_kernel<<<dim3((B * S / 64) * 8), 256, 0, stream>>>(enc, Wh, whe);
  attn_fused_kernel<<<dim3(B * (T / TT)), 256, 0, stream>>>(wsq, whe, enc, v, lens, out);
}

// Round 2
// 1946.314 us; speedup vs baseline: 2.2385x; 2.2385x over previous
//
#include <hip/hip_runtime.h>

// Bahdanau attention: B=32, T=512, S=1024, H=512, fp32.
// out = context [B,T,H] ++ attn_last [B,S]
// ws  = Wsq [B,T,H] (pre-scaled by 2*log2e) ++ WheT [B,H,S] (pre-scaled) -> 96MB.

constexpr int B = 32, T = 512, S = 1024, H = 512;
constexpr int TT = 8;  // timesteps per attn block
constexpr float C2LOG2E = 2.88539008177792681f;  // 2*log2(e)

typedef float vf4 __attribute__((ext_vector_type(4)));

#define DEVI __device__ __forceinline__

// C = A[M][512] * W[512][512]^T, scaled. TRANS=false: C[m][o]. TRANS=true:
// C stored as [b][o][s] with m = b*S + s (requires 64-row tiles aligned in-batch).
template <bool TRANS>
__global__ __launch_bounds__(256)
void matmul_nt_kernel(const float* __restrict__ A, const float* __restrict__ W,
                      float* __restrict__ Cout, float scale) {
  constexpr int K = H, N = H, BM = 64, BN = 64, BK = 16;
  __shared__ __align__(16) float As[BK][BM + 4];
  __shared__ __align__(16) float Bs[BK][BN + 4];
  const int nbx = N / BN;  // 8
  const int bx = blockIdx.x % nbx, by = blockIdx.x / nbx;
  const int tid = threadIdx.x;
  const int tx = tid & 15, ty = tid >> 4;
  const int row0 = by * BM, col0 = bx * BN;
  const int lr = tid >> 2, lk = (tid & 3) * 4;
  float acc[4][4] = {};
  for (int k0 = 0; k0 < K; k0 += BK) {
    float4 av = *(const float4*)&A[(size_t)(row0 + lr) * K + k0 + lk];
    float4 wv = *(const float4*)&W[(size_t)(col0 + lr) * K + k0 + lk];
    __syncthreads();
    As[lk + 0][lr] = av.x; As[lk + 1][lr] = av.y; As[lk + 2][lr] = av.z; As[lk + 3][lr] = av.w;
    Bs[lk + 0][lr] = wv.x; Bs[lk + 1][lr] = wv.y; Bs[lk + 2][lr] = wv.z; Bs[lk + 3][lr] = wv.w;
    __syncthreads();
#pragma unroll
    for (int k = 0; k < BK; ++k) {
      float4 a4 = *(const float4*)&As[k][ty * 4];
      float4 w4 = *(const float4*)&Bs[k][tx * 4];
      float a[4] = {a4.x, a4.y, a4.z, a4.w};
      float w[4] = {w4.x, w4.y, w4.z, w4.w};
#pragma unroll
      for (int i = 0; i < 4; ++i)
#pragma unroll
        for (int j = 0; j < 4; ++j) acc[i][j] = __builtin_fmaf(a[i], w[j], acc[i][j]);
    }
  }
  if (!TRANS) {
#pragma unroll
    for (int i = 0; i < 4; ++i) {
      vf4 o = {acc[i][0] * scale, acc[i][1] * scale, acc[i][2] * scale, acc[i][3] * scale};
      *(vf4*)&Cout[(size_t)(row0 + ty * 4 + i) * N + col0 + tx * 4] = o;
    }
  } else {
    const int b = row0 / S;
    const int sl = (row0 % S) + ty * 4;
#pragma unroll
    for (int j = 0; j < 4; ++j) {
      vf4 o = {acc[0][j] * scale, acc[1][j] * scale, acc[2][j] * scale, acc[3][j] * scale};
      *(vf4*)&Cout[((size_t)b * H + col0 + tx * 4 + j) * S + sl] = o;
    }
  }
}

DEVI void upd4(float (&a)[4], float q, float vv, vf4 e) {
#pragma unroll
  for (int s = 0; s < 4; ++s) {
    float x = __builtin_amdgcn_exp2f(q + e[s]);        // e^{2(qh+eh)}
    a[s] = __builtin_fmaf(vv, __builtin_amdgcn_rcpf(x + 1.0f), a[s]);
  }
}

// Fused: scores -> masked softmax -> context. One block = (b, 8 timesteps).
__global__ __launch_bounds__(256, 3)
void attn_fused_kernel(const float* __restrict__ wsq, const float* __restrict__ wheT,
                       const float* __restrict__ enc, const float* __restrict__ v,
                       const int* __restrict__ lens, float* __restrict__ out) {
  __shared__ __align__(16) float s_wsq[TT][H];  // 16 KB (broadcast reads)
  __shared__ __align__(16) float s_v[H];        // 2 KB  (holds -2*v)
  __shared__ __align__(16) float s_sc[TT][S];   // 32 KB: scores, then p in place
  __shared__ float s_rs[TT];

  // XCD-locality: each XCD (blockIdx%8) owns 4 consecutive batches.
  const int xcd = blockIdx.x & 7;
  const int jj = blockIdx.x >> 3;           // 0..255
  const int b = xcd * 4 + (jj >> 6);        // 0..31
  const int tt = jj & 63;                   // 0..63
  const int tid = threadIdx.x;
  const int len = lens[b];

  {  // stage wsq rows (pre-scaled) + v*(-2)
    int r = tid >> 5, c0 = (tid & 31) * 4;
#pragma unroll
    for (int u = 0; u < 4; ++u) {
      int c = c0 + u * 128;
      *(vf4*)&s_wsq[r][c] = *(const vf4*)&wsq[((size_t)b * T + tt * TT + r) * H + c];
    }
    if (tid < H / 4) {
      vf4 t4 = *(const vf4*)&v[tid * 4];
      *(vf4*)&s_v[tid * 4] = t4 * -2.0f;
    }
  }
  __syncthreads();

  // ---- Phase A: scores. Thread owns 4 consecutive s for all 8 t. ----
  {
    const int s0 = tid * 4;
    float acc[TT][4] = {};
    const float* eb = wheT + (size_t)b * H * S + s0;
    for (int h = 0; h < H; h += 4) {
      vf4 e0 = *(const vf4*)(eb + (size_t)(h + 0) * S);
      vf4 e1 = *(const vf4*)(eb + (size_t)(h + 1) * S);
      vf4 e2 = *(const vf4*)(eb + (size_t)(h + 2) * S);
      vf4 e3 = *(const vf4*)(eb + (size_t)(h + 3) * S);
      vf4 vv = *(const vf4*)&s_v[h];
      vf4 q[TT];
#pragma unroll
      for (int t = 0; t < TT; ++t) q[t] = *(const vf4*)&s_wsq[t][h];
#pragma unroll
      for (int t = 0; t < TT; ++t) {
        upd4(acc[t], q[t][0], vv[0], e0);
        upd4(acc[t], q[t][1], vv[1], e1);
        upd4(acc[t], q[t][2], vv[2], e2);
        upd4(acc[t], q[t][3], vv[3], e3);
      }
    }
#pragma unroll
    for (int t = 0; t < TT; ++t) {
      vf4 o = {acc[t][0], acc[t][1], acc[t][2], acc[t][3]};
      *(vf4*)&s_sc[t][s0] = o;
    }
  }
  __syncthreads();

  // ---- Phase B: masked softmax per row; wave w handles rows 2w, 2w+1 ----
  {
    const int wv = tid >> 6, lane = tid & 63;
#pragma unroll
    for (int j = 0; j < 2; ++j) {
      const int tr = wv * 2 + j;
      float vals[S / 64], ps[S / 64];
      float m = -3.0e38f;
#pragma unroll
      for (int i = 0; i < S / 64; ++i) {
        int s = lane + 64 * i;
        vals[i] = s_sc[tr][s];
        if (s < len) m = fmaxf(m, vals[i]);
      }
#pragma unroll
      for (int o = 1; o < 64; o <<= 1) m = fmaxf(m, __shfl_xor(m, o, 64));
      float sum = 0.f;
#pragma unroll
      for (int i = 0; i < S / 64; ++i) {
        int s = lane + 64 * i;
        float p = (s < len) ? __builtin_amdgcn_exp2f((vals[i] - m) * 1.44269504088896341f) : 0.f;
        ps[i] = p;
        sum += p;
      }
#pragma unroll
      for (int o = 1; o < 64; o <<= 1) sum += __shfl_xor(sum, o, 64);
      float rs = 1.0f / sum;
#pragma unroll
      for (int i = 0; i < S / 64; ++i) s_sc[tr][lane + 64 * i] = ps[i];
      if (lane == 0) s_rs[tr] = rs;
      if (tt == T / TT - 1 && tr == TT - 1) {  // last timestep: attention weights
#pragma unroll
        for (int i = 0; i < S / 64; ++i)
          out[(size_t)B * T * H + (size_t)b * S + lane + 64 * i] = ps[i] * rs;
      }
    }
  }
  __syncthreads();

  // ---- Phase C: ctx[t][h] = sum_s p[t][s] * enc[b][s][h] ----
  {
    const int tg = tid >> 6, lane = tid & 63;  // t in {tg, tg+4}
    const int h0 = lane * 4, h1 = 256 + lane * 4;
    float acc0[8] = {}, acc1[8] = {};
#pragma unroll 2
    for (int s = 0; s < S; ++s) {
      float p0 = s_sc[tg][s];
      float p1 = s_sc[tg + 4][s];
      const float* er = enc + ((size_t)b * S + s) * H;
      float4 e0 = *(const float4*)(er + h0);
      float4 e1 = *(const float4*)(er + h1);
      float ev[8] = {e0.x, e0.y, e0.z, e0.w, e1.x, e1.y, e1.z, e1.w};
#pragma unroll
      for (int k = 0; k < 8; ++k) {
        acc0[k] = __builtin_fmaf(p0, ev[k], acc0[k]);
        acc1[k] = __builtin_fmaf(p1, ev[k], acc1[k]);
      }
    }
    const float rs0 = s_rs[tg], rs1 = s_rs[tg + 4];
    const size_t base0 = ((size_t)b * T + tt * TT + tg) * H;
    const size_t base1 = ((size_t)b * T + tt * TT + tg + 4) * H;
    float4 o;
    o = make_float4(acc0[0] * rs0, acc0[1] * rs0, acc0[2] * rs0, acc0[3] * rs0);
    *(float4*)&out[base0 + h0] = o;
    o = make_float4(acc0[4] * rs0, acc0[5] * rs0, acc0[6] * rs0, acc0[7] * rs0);
    *(float4*)&out[base0 + h1] = o;
    o = make_float4(acc1[0] * rs1, acc1[1] * rs1, acc1[2] * rs1, acc1[3] * rs1);
    *(float4*)&out[base1 + h0] = o;
    o = make_float4(acc1[4] * rs1, acc1[5] * rs1, acc1[6] * rs1, acc1[7] * rs1);
    *(float4*)&out[base1 + h1] = o;
  }
}

extern "C" void kernel_launch(void* const* d_in, const int* in_sizes, int n_in,
                              void* d_out, int out_size, void* d_ws, size_t ws_size,
                              hipStream_t stream) {
  const float* query = (const float*)d_in[0];  // [B,T,H]
  const float* enc   = (const float*)d_in[1];  // [B,S,H]
  const int*   lens  = (const int*)d_in[2];    // [B]
  const float* Ws    = (const float*)d_in[3];  // [H,H]
  const float* Wh    = (const float*)d_in[4];  // [H,H]
  const float* v     = (const float*)d_in[5];  // [H]
  float* out = (float*)d_out;
  float* wsq  = (float*)d_ws;                  // [B,T,H], pre-scaled
  float* wheT = wsq + (size_t)B * T * H;       // [B,H,S], pre-scaled

  matmul_nt_kernel<false><<<dim3((B * T / 64) * 8), 256, 0, stream>>>(query, Ws, wsq, C2LOG2E);
  matmul_nt_kernel<true><<<dim3((B * S / 64) * 8), 256, 0, stream>>>(enc, Wh, wheT, C2LOG2E);
  attn_fused_kernel<<<dim3(B * (T / TT)), 256, 0, stream>>>(wsq, wheT, enc, v, lens, out);
}

// Round 3
// 1357.062 us; speedup vs baseline: 3.2105x; 1.4342x over previous
//
#include <hip/hip_runtime.h>

// Bahdanau attention: B=32, T=512, S=1024, H=512, fp32.
// out = context [B,T,H] ++ attn_last [B,S]
// ws  = Wsq [B,T,H] (pre-scaled by 2*log2e) ++ WheT [B,H,S] (pre-scaled) -> 96MB.
// Score trick: softmax shift-invariance => score' = sum_h (-2 v_h) / (1 + e^{2(q+e)}),
// and e^{2(q+e)} = Q*E with Q,E precomputed exp2's -> 2 VALU + 1 rcp per element.

constexpr int B = 32, T = 512, S = 1024, H = 512;
constexpr int TT = 8;  // timesteps per attn block
constexpr float C2LOG2E = 2.88539008177792681f;  // 2*log2(e)

typedef float vf4 __attribute__((ext_vector_type(4)));

#define DEVI __device__ __forceinline__

DEVI vf4 exp2v(vf4 x) {
  vf4 r;
  r[0] = __builtin_amdgcn_exp2f(x[0]);
  r[1] = __builtin_amdgcn_exp2f(x[1]);
  r[2] = __builtin_amdgcn_exp2f(x[2]);
  r[3] = __builtin_amdgcn_exp2f(x[3]);
  return r;
}

// C = A[M][512] * W[512][512]^T, scaled. TRANS=false: C[m][o]. TRANS=true:
// C stored as [b][o][s] with m = b*S + s; tiles fully beyond src_length skipped.
template <bool TRANS>
__global__ __launch_bounds__(256)
void matmul_nt_kernel(const float* __restrict__ A, const float* __restrict__ W,
                      float* __restrict__ Cout, float scale, const int* __restrict__ lens) {
  constexpr int K = H, N = H, BM = 64, BN = 64, BK = 16;
  __shared__ __align__(16) float As[BK][BM + 4];
  __shared__ __align__(16) float Bs[BK][BN + 4];
  const int nbx = N / BN;  // 8
  const int bx = blockIdx.x % nbx, by = blockIdx.x / nbx;
  const int row0 = by * BM, col0 = bx * BN;
  if (TRANS) {  // rows row0..row0+63 are one batch; skip if fully masked
    if ((row0 % S) >= lens[row0 / S]) return;
  }
  const int tid = threadIdx.x;
  const int tx = tid & 15, ty = tid >> 4;
  const int lr = tid >> 2, lk = (tid & 3) * 4;
  float acc[4][4] = {};
  for (int k0 = 0; k0 < K; k0 += BK) {
    float4 av = *(const float4*)&A[(size_t)(row0 + lr) * K + k0 + lk];
    float4 wv = *(const float4*)&W[(size_t)(col0 + lr) * K + k0 + lk];
    __syncthreads();
    As[lk + 0][lr] = av.x; As[lk + 1][lr] = av.y; As[lk + 2][lr] = av.z; As[lk + 3][lr] = av.w;
    Bs[lk + 0][lr] = wv.x; Bs[lk + 1][lr] = wv.y; Bs[lk + 2][lr] = wv.z; Bs[lk + 3][lr] = wv.w;
    __syncthreads();
#pragma unroll
    for (int k = 0; k < BK; ++k) {
      float4 a4 = *(const float4*)&As[k][ty * 4];
      float4 w4 = *(const float4*)&Bs[k][tx * 4];
      float a[4] = {a4.x, a4.y, a4.z, a4.w};
      float w[4] = {w4.x, w4.y, w4.z, w4.w};
#pragma unroll
      for (int i = 0; i < 4; ++i)
#pragma unroll
        for (int j = 0; j < 4; ++j) acc[i][j] = __builtin_fmaf(a[i], w[j], acc[i][j]);
    }
  }
  if (!TRANS) {
#pragma unroll
    for (int i = 0; i < 4; ++i) {
      vf4 o = {acc[i][0] * scale, acc[i][1] * scale, acc[i][2] * scale, acc[i][3] * scale};
      *(vf4*)&Cout[(size_t)(row0 + ty * 4 + i) * N + col0 + tx * 4] = o;
    }
  } else {
    const int b = row0 / S;
    const int sl = (row0 % S) + ty * 4;
#pragma unroll
    for (int j = 0; j < 4; ++j) {
      vf4 o = {acc[0][j] * scale, acc[1][j] * scale, acc[2][j] * scale, acc[3][j] * scale};
      *(vf4*)&Cout[((size_t)b * H + col0 + tx * 4 + j) * S + sl] = o;
    }
  }
}

// x = Q*E + 1 (one fma); acc += vv * rcp(x).
DEVI void upd4(float (&a)[4], float Q, float vv, vf4 E) {
#pragma unroll
  for (int s = 0; s < 4; ++s) {
    float x = __builtin_fmaf(Q, E[s], 1.0f);
    a[s] = __builtin_fmaf(vv, __builtin_amdgcn_rcpf(x), a[s]);
  }
}

// Fused: scores -> masked softmax -> context. One block = (b, 8 timesteps).
__global__ __launch_bounds__(256, 3)
void attn_fused_kernel(const float* __restrict__ wsq, const float* __restrict__ wheT,
                       const float* __restrict__ enc, const float* __restrict__ v,
                       const int* __restrict__ lens, float* __restrict__ out) {
  __shared__ __align__(16) float s_wsq[TT][H];  // 16 KB: Q = e^{2 q}
  __shared__ __align__(16) float s_v[H];        // 2 KB : -2*v
  __shared__ __align__(16) float s_sc[TT][S];   // 32 KB: scores, then p in place
  __shared__ float s_rs[TT];

  const int b = blockIdx.x & (B - 1);
  const int tt = blockIdx.x >> 5;  // 0..63
  const int tid = threadIdx.x;
  const int len = lens[b];

  {  // stage Q = exp2(wsq_scaled) + v*(-2)
    int r = tid >> 5, c0 = (tid & 31) * 4;
#pragma unroll
    for (int u = 0; u < 4; ++u) {
      int c = c0 + u * 128;
      vf4 t4 = *(const vf4*)&wsq[((size_t)b * T + tt * TT + r) * H + c];
      *(vf4*)&s_wsq[r][c] = exp2v(t4);
    }
    if (tid < H / 4) {
      vf4 t4 = *(const vf4*)&v[tid * 4];
      *(vf4*)&s_v[tid * 4] = t4 * -2.0f;
    }
  }
  __syncthreads();

  // ---- Phase A: scores. Thread owns 4 consecutive s for all 8 t; waves
  // whose whole s-range is masked skip entirely. ----
  {
    const int s0 = tid * 4;
    if (s0 < len) {
      float acc[TT][4] = {};
      const float* eb = wheT + (size_t)b * H * S + s0;
      for (int h = 0; h < H; h += 4) {
        vf4 e0 = exp2v(*(const vf4*)(eb + (size_t)(h + 0) * S));
        vf4 e1 = exp2v(*(const vf4*)(eb + (size_t)(h + 1) * S));
        vf4 e2 = exp2v(*(const vf4*)(eb + (size_t)(h + 2) * S));
        vf4 e3 = exp2v(*(const vf4*)(eb + (size_t)(h + 3) * S));
        vf4 vv = *(const vf4*)&s_v[h];
        vf4 q[TT];
#pragma unroll
        for (int t = 0; t < TT; ++t) q[t] = *(const vf4*)&s_wsq[t][h];
#pragma unroll
        for (int t = 0; t < TT; ++t) {
          upd4(acc[t], q[t][0], vv[0], e0);
          upd4(acc[t], q[t][1], vv[1], e1);
          upd4(acc[t], q[t][2], vv[2], e2);
          upd4(acc[t], q[t][3], vv[3], e3);
        }
      }
#pragma unroll
      for (int t = 0; t < TT; ++t) {
        vf4 o = {acc[t][0], acc[t][1], acc[t][2], acc[t][3]};
        *(vf4*)&s_sc[t][s0] = o;
      }
    }
  }
  __syncthreads();

  // ---- Phase B: masked softmax per row; wave w handles rows 2w, 2w+1 ----
  {
    const int wv = tid >> 6, lane = tid & 63;
#pragma unroll
    for (int j = 0; j < 2; ++j) {
      const int tr = wv * 2 + j;
      float vals[S / 64], ps[S / 64];
      float m = -3.0e38f;
#pragma unroll
      for (int i = 0; i < S / 64; ++i) {
        int s = lane + 64 * i;
        vals[i] = s_sc[tr][s];
        if (s < len) m = fmaxf(m, vals[i]);
      }
#pragma unroll
      for (int o = 1; o < 64; o <<= 1) m = fmaxf(m, __shfl_xor(m, o, 64));
      float sum = 0.f;
#pragma unroll
      for (int i = 0; i < S / 64; ++i) {
        int s = lane + 64 * i;
        float p = (s < len) ? __builtin_amdgcn_exp2f((vals[i] - m) * 1.44269504088896341f) : 0.f;
        ps[i] = p;
        sum += p;
      }
#pragma unroll
      for (int o = 1; o < 64; o <<= 1) sum += __shfl_xor(sum, o, 64);
      float rs = 1.0f / sum;
#pragma unroll
      for (int i = 0; i < S / 64; ++i) s_sc[tr][lane + 64 * i] = ps[i];
      if (lane == 0) s_rs[tr] = rs;
      if (tt == T / TT - 1 && tr == TT - 1) {  // last timestep: attention weights
#pragma unroll
        for (int i = 0; i < S / 64; ++i)
          out[(size_t)B * T * H + (size_t)b * S + lane + 64 * i] = ps[i] * rs;
      }
    }
  }
  __syncthreads();

  // ---- Phase C: ctx[t][h] = sum_{s<len} p[t][s] * enc[b][s][h] ----
  {
    const int tg = tid >> 6, lane = tid & 63;  // t in {tg, tg+4}
    const int h0 = lane * 4, h1 = 256 + lane * 4;
    float acc0[8] = {}, acc1[8] = {};
#pragma unroll 2
    for (int s = 0; s < len; ++s) {
      float p0 = s_sc[tg][s];
      float p1 = s_sc[tg + 4][s];
      const float* er = enc + ((size_t)b * S + s) * H;
      float4 e0 = *(const float4*)(er + h0);
      float4 e1 = *(const float4*)(er + h1);
      float ev[8] = {e0.x, e0.y, e0.z, e0.w, e1.x, e1.y, e1.z, e1.w};
#pragma unroll
      for (int k = 0; k < 8; ++k) {
        acc0[k] = __builtin_fmaf(p0, ev[k], acc0[k]);
        acc1[k] = __builtin_fmaf(p1, ev[k], acc1[k]);
      }
    }
    const float rs0 = s_rs[tg], rs1 = s_rs[tg + 4];
    const size_t base0 = ((size_t)b * T + tt * TT + tg) * H;
    const size_t base1 = ((size_t)b * T + tt * TT + tg + 4) * H;
    float4 o;
    o = make_float4(acc0[0] * rs0, acc0[1] * rs0, acc0[2] * rs0, acc0[3] * rs0);
    *(float4*)&out[base0 + h0] = o;
    o = make_float4(acc0[4] * rs0, acc0[5] * rs0, acc0[6] * rs0, acc0[7] * rs0);
    *(float4*)&out[base0 + h1] = o;
    o = make_float4(acc1[0] * rs1, acc1[1] * rs1, acc1[2] * rs1, acc1[3] * rs1);
    *(float4*)&out[base1 + h0] = o;
    o = make_float4(acc1[4] * rs1, acc1[5] * rs1, acc1[6] * rs1, acc1[7] * rs1);
    *(float4*)&out[base1 + h1] = o;
  }
}

extern "C" void kernel_launch(void* const* d_in, const int* in_sizes, int n_in,
                              void* d_out, int out_size, void* d_ws, size_t ws_size,
                              hipStream_t stream) {
  const float* query = (const float*)d_in[0];  // [B,T,H]
  const float* enc   = (const float*)d_in[1];  // [B,S,H]
  const int*   lens  = (const int*)d_in[2];    // [B]
  const float* Ws    = (const float*)d_in[3];  // [H,H]
  const float* Wh    = (const float*)d_in[4];  // [H,H]
  const float* v     = (const float*)d_in[5];  // [H]
  float* out = (float*)d_out;
  float* wsq  = (float*)d_ws;                  // [B,T,H], pre-scaled
  float* wheT = wsq + (size_t)B * T * H;       // [B,H,S], pre-scaled

  matmul_nt_kernel<false><<<dim3((B * T / 64) * 8), 256, 0, stream>>>(query, Ws, wsq, C2LOG2E, nullptr);
  matmul_nt_kernel<true><<<dim3((B * S / 64) * 8), 256, 0, stream>>>(enc, Wh, wheT, C2LOG2E, lens);
  attn_fused_kernel<<<dim3(B * (T / TT)), 256, 0, stream>>>(wsq, wheT, enc, v, lens, out);
}

// Round 4
// 1076.015 us; speedup vs baseline: 4.0491x; 1.2612x over previous
//
#include <hip/hip_runtime.h>

// Bahdanau attention: B=32, T=512, S=1024, H=512, fp32.
// out = context [B,T,H] ++ attn_last [B,S]
// ws  = Q [B,T,H] ++ E [B,H,S], where Q = e^{2*Wsq}, E = e^{2*Whe} (exp2 of
// pre-scaled matmul results, computed in the matmul epilogues).
// Score trick: softmax shift-invariance => score' = sum_h (-2 v_h) / (1 + Q*E)
// -> 2 VALU + 1 rcp per (t,s,h) element, no per-element transcendental chain.

constexpr int B = 32, T = 512, S = 1024, H = 512;
constexpr int TT = 4;  // timesteps per attn block
constexpr float C2LOG2E = 2.88539008177792681f;  // 2*log2(e)

typedef float vf4 __attribute__((ext_vector_type(4)));

#define DEVI __device__ __forceinline__

DEVI vf4 exp2v(vf4 x) {
  vf4 r;
  r[0] = __builtin_amdgcn_exp2f(x[0]);
  r[1] = __builtin_amdgcn_exp2f(x[1]);
  r[2] = __builtin_amdgcn_exp2f(x[2]);
  r[3] = __builtin_amdgcn_exp2f(x[3]);
  return r;
}

// C = exp2(scale * A[M][512] * W[512][512]^T). TRANS=false: C[m][o]. TRANS=true:
// C stored as [b][o][s] with m = b*S + s; tiles fully beyond src_length skipped.
template <bool TRANS>
__global__ __launch_bounds__(256)
void matmul_nt_kernel(const float* __restrict__ A, const float* __restrict__ W,
                      float* __restrict__ Cout, float scale, const int* __restrict__ lens) {
  constexpr int K = H, N = H, BM = 64, BN = 64, BK = 16;
  __shared__ __align__(16) float As[BK][BM + 4];
  __shared__ __align__(16) float Bs[BK][BN + 4];
  const int nbx = N / BN;  // 8
  const int bx = blockIdx.x % nbx, by = blockIdx.x / nbx;
  const int row0 = by * BM, col0 = bx * BN;
  if (TRANS) {  // rows row0..row0+63 are one batch; skip if fully masked
    if ((row0 % S) >= lens[row0 / S]) return;
  }
  const int tid = threadIdx.x;
  const int tx = tid & 15, ty = tid >> 4;
  const int lr = tid >> 2, lk = (tid & 3) * 4;
  float acc[4][4] = {};
  for (int k0 = 0; k0 < K; k0 += BK) {
    float4 av = *(const float4*)&A[(size_t)(row0 + lr) * K + k0 + lk];
    float4 wv = *(const float4*)&W[(size_t)(col0 + lr) * K + k0 + lk];
    __syncthreads();
    As[lk + 0][lr] = av.x; As[lk + 1][lr] = av.y; As[lk + 2][lr] = av.z; As[lk + 3][lr] = av.w;
    Bs[lk + 0][lr] = wv.x; Bs[lk + 1][lr] = wv.y; Bs[lk + 2][lr] = wv.z; Bs[lk + 3][lr] = wv.w;
    __syncthreads();
#pragma unroll
    for (int k = 0; k < BK; ++k) {
      float4 a4 = *(const float4*)&As[k][ty * 4];
      float4 w4 = *(const float4*)&Bs[k][tx * 4];
      float a[4] = {a4.x, a4.y, a4.z, a4.w};
      float w[4] = {w4.x, w4.y, w4.z, w4.w};
#pragma unroll
      for (int i = 0; i < 4; ++i)
#pragma unroll
        for (int j = 0; j < 4; ++j) acc[i][j] = __builtin_fmaf(a[i], w[j], acc[i][j]);
    }
  }
  if (!TRANS) {
#pragma unroll
    for (int i = 0; i < 4; ++i) {
      vf4 o = {acc[i][0] * scale, acc[i][1] * scale, acc[i][2] * scale, acc[i][3] * scale};
      *(vf4*)&Cout[(size_t)(row0 + ty * 4 + i) * N + col0 + tx * 4] = exp2v(o);
    }
  } else {
    const int b = row0 / S;
    const int sl = (row0 % S) + ty * 4;
#pragma unroll
    for (int j = 0; j < 4; ++j) {
      vf4 o = {acc[0][j] * scale, acc[1][j] * scale, acc[2][j] * scale, acc[3][j] * scale};
      *(vf4*)&Cout[((size_t)b * H + col0 + tx * 4 + j) * S + sl] = exp2v(o);
    }
  }
}

// x = Q*E + 1 (one fma); acc += vv * rcp(x).
DEVI void upd4(float (&a)[4], float Q, float vv, vf4 E) {
#pragma unroll
  for (int s = 0; s < 4; ++s) {
    float x = __builtin_fmaf(Q, E[s], 1.0f);
    a[s] = __builtin_fmaf(vv, __builtin_amdgcn_rcpf(x), a[s]);
  }
}

// Fused: scores -> masked softmax -> context. One block = (b, 4 timesteps).
__global__ __launch_bounds__(256, 6)
void attn_fused_kernel(const float* __restrict__ wsq, const float* __restrict__ wheT,
                       const float* __restrict__ enc, const float* __restrict__ v,
                       const int* __restrict__ lens, float* __restrict__ out) {
  __shared__ __align__(16) float s_wsq[TT][H];  // 8 KB : Q rows
  __shared__ __align__(16) float s_v[H];        // 2 KB : -2*v
  __shared__ __align__(16) float s_sc[TT][S];   // 16 KB: scores, then p in place
  __shared__ float s_rs[TT];
  __shared__ long long s_w[32];
  __shared__ int s_bsel;

  const int tid = threadIdx.x;
  const int xcd = blockIdx.x & 7;     // dispatch round-robin heuristic
  const int j = blockIdx.x >> 3;      // 0..511
  const int slot = j >> 7;            // 0..3: which of this XCD's 4 batches
  const int tt = j & 127;             // 0..127 t-tile within batch

  // Runtime snake load-balance: rank batches by Phase-A weight (desc), XCD x
  // gets ranks {x, 15-x, 16+x, 31-x} -> balanced work, batch-major locality.
  if (tid < 32) {
    int l = lens[tid];
    s_w[tid] = ((long long)((l + 255) >> 8) << 20) + l * 32 + tid;  // unique
  }
  __syncthreads();
  if (tid < 32) {
    long long wb = s_w[tid];
    int rank = 0;
#pragma unroll
    for (int b2 = 0; b2 < 32; ++b2) rank += (s_w[b2] > wb);
    int myrank = slot * 8 + ((slot & 1) ? (7 - xcd) : xcd);
    if (rank == myrank) s_bsel = tid;
  }
  // staging of v can proceed before we know b
  if (tid >= 128 && tid < 256) {
    int c = (tid - 128) * 4;
    vf4 t4 = *(const vf4*)&v[c];
    *(vf4*)&s_v[c] = t4 * -2.0f;
  }
  __syncthreads();
  const int b = s_bsel;
  const int len = lens[b];

  {  // stage Q rows for this t-tile
    int r = tid >> 6, c0 = (tid & 63) * 4;
#pragma unroll
    for (int u = 0; u < 2; ++u) {
      int c = c0 + u * 256;
      *(vf4*)&s_wsq[r][c] = *(const vf4*)&wsq[((size_t)b * T + tt * TT + r) * H + c];
    }
  }
  __syncthreads();

  // ---- Phase A: scores. Thread owns 4 consecutive s for all 4 t; waves
  // whose whole s-range is masked skip entirely. E prefetched 1 iter ahead. ----
  {
    const int s0 = tid * 4;
    if (s0 < len) {
      float acc[TT][4] = {};
      const float* eb = wheT + (size_t)b * H * S + s0;
      vf4 en[4];
#pragma unroll
      for (int r = 0; r < 4; ++r) en[r] = *(const vf4*)(eb + (size_t)r * S);
      for (int h = 0; h < H; h += 4) {
        vf4 ec[4];
#pragma unroll
        for (int r = 0; r < 4; ++r) ec[r] = en[r];
        if (h + 4 < H) {
#pragma unroll
          for (int r = 0; r < 4; ++r) en[r] = *(const vf4*)(eb + (size_t)(h + 4 + r) * S);
        }
        vf4 vv = *(const vf4*)&s_v[h];
#pragma unroll
        for (int t = 0; t < TT; ++t) {
          vf4 q = *(const vf4*)&s_wsq[t][h];
          upd4(acc[t], q[0], vv[0], ec[0]);
          upd4(acc[t], q[1], vv[1], ec[1]);
          upd4(acc[t], q[2], vv[2], ec[2]);
          upd4(acc[t], q[3], vv[3], ec[3]);
        }
      }
#pragma unroll
      for (int t = 0; t < TT; ++t) {
        vf4 o = {acc[t][0], acc[t][1], acc[t][2], acc[t][3]};
        *(vf4*)&s_sc[t][s0] = o;
      }
    }
  }
  __syncthreads();

  // ---- Phase B: masked softmax; wave w handles row w ----
  {
    const int tr = tid >> 6, lane = tid & 63;
    float vals[S / 64], ps[S / 64];
    float m = -3.0e38f;
#pragma unroll
    for (int i = 0; i < S / 64; ++i) {
      int s = lane + 64 * i;
      vals[i] = s_sc[tr][s];
      if (s < len) m = fmaxf(m, vals[i]);
    }
#pragma unroll
    for (int o = 1; o < 64; o <<= 1) m = fmaxf(m, __shfl_xor(m, o, 64));
    float sum = 0.f;
#pragma unroll
    for (int i = 0; i < S / 64; ++i) {
      int s = lane + 64 * i;
      float p = (s < len) ? __builtin_amdgcn_exp2f((vals[i] - m) * 1.44269504088896341f) : 0.f;
      ps[i] = p;
      sum += p;
    }
#pragma unroll
    for (int o = 1; o < 64; o <<= 1) sum += __shfl_xor(sum, o, 64);
    float rs = 1.0f / sum;
#pragma unroll
    for (int i = 0; i < S / 64; ++i) s_sc[tr][lane + 64 * i] = ps[i];
    if (lane == 0) s_rs[tr] = rs;
    if (tt == T / TT - 1 && tr == TT - 1) {  // last timestep: attention weights
#pragma unroll
      for (int i = 0; i < S / 64; ++i)
        out[(size_t)B * T * H + (size_t)b * S + lane + 64 * i] = ps[i] * rs;
    }
  }
  __syncthreads();

  // ---- Phase C: ctx[t][h] = sum_{s<len} p[t][s] * enc[b][s][h]; wave = t ----
  {
    const int tg = tid >> 6, lane = tid & 63;
    const int h0 = lane * 4, h1 = 256 + lane * 4;
    float acc[8] = {};
    const float* encb = enc + (size_t)b * S * H;
#pragma unroll 2
    for (int s = 0; s < len; ++s) {
      float p = s_sc[tg][s];
      const float* er = encb + (size_t)s * H;
      float4 e0 = *(const float4*)(er + h0);
      float4 e1 = *(const float4*)(er + h1);
      float ev[8] = {e0.x, e0.y, e0.z, e0.w, e1.x, e1.y, e1.z, e1.w};
#pragma unroll
      for (int k = 0; k < 8; ++k) acc[k] = __builtin_fmaf(p, ev[k], acc[k]);
    }
    const float rs = s_rs[tg];
    const size_t base = ((size_t)b * T + tt * TT + tg) * H;
    float4 o;
    o = make_float4(acc[0] * rs, acc[1] * rs, acc[2] * rs, acc[3] * rs);
    *(float4*)&out[base + h0] = o;
    o = make_float4(acc[4] * rs, acc[5] * rs, acc[6] * rs, acc[7] * rs);
    *(float4*)&out[base + h1] = o;
  }
}

extern "C" void kernel_launch(void* const* d_in, const int* in_sizes, int n_in,
                              void* d_out, int out_size, void* d_ws, size_t ws_size,
                              hipStream_t stream) {
  const float* query = (const float*)d_in[0];  // [B,T,H]
  const float* enc   = (const float*)d_in[1];  // [B,S,H]
  const int*   lens  = (const int*)d_in[2];    // [B]
  const float* Ws    = (const float*)d_in[3];  // [H,H]
  const float* Wh    = (const float*)d_in[4];  // [H,H]
  const float* v     = (const float*)d_in[5];  // [H]
  float* out = (float*)d_out;
  float* wsq  = (float*)d_ws;                  // [B,T,H] = Q
  float* wheT = wsq + (size_t)B * T * H;       // [B,H,S] = E

  matmul_nt_kernel<false><<<dim3((B * T / 64) * 8), 256, 0, stream>>>(query, Ws, wsq, C2LOG2E, nullptr);
  matmul_nt_kernel<true><<<dim3((B * S / 64) * 8), 256, 0, stream>>>(enc, Wh, wheT, C2LOG2E, lens);
  attn_fused_kernel<<<dim3(B * (T / TT)), 256, 0, stream>>>(wsq, wheT, enc, v, lens, out);
}

// Round 5
// 976.487 us; speedup vs baseline: 4.4618x; 1.1019x over previous
//
#include <hip/hip_runtime.h>

// Bahdanau attention: B=32, T=512, S=1024, H=512, fp32.
// out = context [B,T,H] ++ attn_last [B,S]
// ws  = Q [B,T,H] ++ E4 [B,H/4,S,4]; Q = e^{2*Wsq}, E = e^{2*Whe} (clamped
// exp2 in matmul epilogues). Score trick: softmax shift-invariance =>
// score' = sum_h (-2 v_h) / (1 + Q*E); h-quads combined by a reciprocal tree:
// sum_i v_i/a_i = n/d  ->  14 VALU + 1 rcp per 4 elements (9 cyc/wave-elem).

constexpr int B = 32, T = 512, S = 1024, H = 512;
constexpr int TT = 4;  // timesteps per attn block
constexpr float C2LOG2E = 2.88539008177792681f;  // 2*log2(e)

typedef float vf4 __attribute__((ext_vector_type(4)));

#define DEVI __device__ __forceinline__

DEVI vf4 exp2clampv(vf4 x) {
  vf4 r;
#pragma unroll
  for (int i = 0; i < 4; ++i)
    r[i] = __builtin_amdgcn_exp2f(fminf(fmaxf(x[i], -15.f), 15.f));
  return r;
}

// C = exp2(clamp(scale * A[M][512] * W[512][512]^T)). TRANS=false: C[m][o].
// TRANS=true: C as [b][o/4][s][4], m = b*S + s; fully-masked s-tiles skipped.
template <bool TRANS>
__global__ __launch_bounds__(256)
void matmul_nt_kernel(const float* __restrict__ A, const float* __restrict__ W,
                      float* __restrict__ Cout, float scale, const int* __restrict__ lens) {
  constexpr int K = H, N = H, BM = 64, BN = 64, BK = 16;
  __shared__ __align__(16) float As[BK][BM + 4];
  __shared__ __align__(16) float Bs[BK][BN + 4];
  const int nbx = N / BN;  // 8
  const int bx = blockIdx.x % nbx, by = blockIdx.x / nbx;
  const int row0 = by * BM, col0 = bx * BN;
  if (TRANS) {  // rows row0..row0+63 are one batch; skip if fully masked
    if ((row0 % S) >= lens[row0 / S]) return;
  }
  const int tid = threadIdx.x;
  const int tx = tid & 15, ty = tid >> 4;
  const int lr = tid >> 2, lk = (tid & 3) * 4;
  float acc[4][4] = {};
  for (int k0 = 0; k0 < K; k0 += BK) {
    float4 av = *(const float4*)&A[(size_t)(row0 + lr) * K + k0 + lk];
    float4 wv = *(const float4*)&W[(size_t)(col0 + lr) * K + k0 + lk];
    __syncthreads();
    As[lk + 0][lr] = av.x; As[lk + 1][lr] = av.y; As[lk + 2][lr] = av.z; As[lk + 3][lr] = av.w;
    Bs[lk + 0][lr] = wv.x; Bs[lk + 1][lr] = wv.y; Bs[lk + 2][lr] = wv.z; Bs[lk + 3][lr] = wv.w;
    __syncthreads();
#pragma unroll
    for (int k = 0; k < BK; ++k) {
      float4 a4 = *(const float4*)&As[k][ty * 4];
      float4 w4 = *(const float4*)&Bs[k][tx * 4];
      float a[4] = {a4.x, a4.y, a4.z, a4.w};
      float w[4] = {w4.x, w4.y, w4.z, w4.w};
#pragma unroll
      for (int i = 0; i < 4; ++i)
#pragma unroll
        for (int j = 0; j < 4; ++j) acc[i][j] = __builtin_fmaf(a[i], w[j], acc[i][j]);
    }
  }
  if (!TRANS) {
#pragma unroll
    for (int i = 0; i < 4; ++i) {
      vf4 o = {acc[i][0] * scale, acc[i][1] * scale, acc[i][2] * scale, acc[i][3] * scale};
      *(vf4*)&Cout[(size_t)(row0 + ty * 4 + i) * N + col0 + tx * 4] = exp2clampv(o);
    }
  } else {
    const int b = row0 / S;
    const int sl = (row0 % S) + ty * 4;
    // E4[b][h4][s][c]: addr = b*H*S + h4*4S + s*4 + c, h4 = col0/4 + tx, c = j
    float* base = Cout + (size_t)b * H * S + (size_t)((col0 >> 2) + tx) * (4 * S);
#pragma unroll
    for (int i = 0; i < 4; ++i) {
      vf4 o = {acc[i][0] * scale, acc[i][1] * scale, acc[i][2] * scale, acc[i][3] * scale};
      *(vf4*)&base[(size_t)(sl + i) * 4] = exp2clampv(o);
    }
  }
}

// Fused: scores -> masked softmax -> context. One block = (b, 4 timesteps).
__global__ __launch_bounds__(256, 6)
void attn_fused_kernel(const float* __restrict__ wsq, const float* __restrict__ wheT,
                       const float* __restrict__ enc, const float* __restrict__ v,
                       const int* __restrict__ lens, float* __restrict__ out) {
  __shared__ __align__(16) float s_wsq[TT][H];  // 8 KB : Q rows
  __shared__ __align__(16) float s_v[H];        // 2 KB : -2*v
  __shared__ __align__(16) float s_sc[TT][S];   // 16 KB: scores, then p in place
  __shared__ float s_rs[TT];
  __shared__ long long s_w[32];
  __shared__ int s_bsel;

  const int tid = threadIdx.x;
  const int xcd = blockIdx.x & 7;     // dispatch round-robin heuristic
  const int j = blockIdx.x >> 3;      // 0..511
  const int slot = j >> 7;            // 0..3: which of this XCD's 4 batches
  const int tt = j & 127;             // 0..127 t-tile within batch

  // Runtime snake load-balance: rank batches by len (desc), XCD x gets ranks
  // {x, 15-x, 16+x, 31-x} -> balanced work, batch-major locality.
  if (tid < 32) {
    int l = lens[tid];
    s_w[tid] = ((long long)l << 8) + tid;  // unique key
  }
  __syncthreads();
  if (tid < 32) {
    long long wb = s_w[tid];
    int rank = 0;
#pragma unroll
    for (int b2 = 0; b2 < 32; ++b2) rank += (s_w[b2] > wb);
    int myrank = slot * 8 + ((slot & 1) ? (7 - xcd) : xcd);
    if (rank == myrank) s_bsel = tid;
  }
  // staging of v can proceed before we know b
  if (tid >= 128 && tid < 256) {
    int c = (tid - 128) * 4;
    vf4 t4 = *(const vf4*)&v[c];
    *(vf4*)&s_v[c] = t4 * -2.0f;
  }
  __syncthreads();
  const int b = s_bsel;
  const int len = lens[b];

  {  // stage Q rows for this t-tile
    int r = tid >> 6, c0 = (tid & 63) * 4;
#pragma unroll
    for (int u = 0; u < 2; ++u) {
      int c = c0 + u * 256;
      *(vf4*)&s_wsq[r][c] = *(const vf4*)&wsq[((size_t)b * T + tt * TT + r) * H + c];
    }
  }
  __syncthreads();

  // ---- Phase A: scores over 64-s strips; wave w takes strips k=(w+tt) mod 4.
  // Thread owns one s for all 4 t; h-quads combined via reciprocal tree. ----
  {
    const int wv = tid >> 6, lane = tid & 63;
    const int NS = (len + 63) >> 6;  // strips actually needed
    const float* e4b = wheT + (size_t)b * H * S;  // [h4][s][4]
    for (int k = (wv + tt) & 3; k < NS; k += 4) {
      const int s = k * 64 + lane;
      const float* ep = e4b + (size_t)s * 4;
      float acc[TT] = {};
      vf4 en = *(const vf4*)ep;
      for (int h4 = 0; h4 < H / 4; ++h4) {
        vf4 e = en;
        if (h4 + 1 < H / 4) en = *(const vf4*)(ep + (size_t)(h4 + 1) * (4 * S));
        vf4 vv = *(const vf4*)&s_v[h4 * 4];
#pragma unroll
        for (int t = 0; t < TT; ++t) {
          vf4 q = *(const vf4*)&s_wsq[t][h4 * 4];
          float a0 = __builtin_fmaf(q[0], e[0], 1.0f);
          float a1 = __builtin_fmaf(q[1], e[1], 1.0f);
          float a2 = __builtin_fmaf(q[2], e[2], 1.0f);
          float a3 = __builtin_fmaf(q[3], e[3], 1.0f);
          float d01 = a0 * a1, d23 = a2 * a3;
          float n01 = vv[0] * a1; n01 = __builtin_fmaf(vv[1], a0, n01);
          float n23 = vv[2] * a3; n23 = __builtin_fmaf(vv[3], a2, n23);
          float d = d01 * d23;
          float n = n01 * d23; n = __builtin_fmaf(n23, d01, n);
          acc[t] = __builtin_fmaf(n, __builtin_amdgcn_rcpf(d), acc[t]);
        }
      }
#pragma unroll
      for (int t = 0; t < TT; ++t) s_sc[t][s] = acc[t];
    }
  }
  __syncthreads();

  // ---- Phase B: masked softmax; wave w handles row w ----
  {
    const int tr = tid >> 6, lane = tid & 63;
    float vals[S / 64], ps[S / 64];
    float m = -3.0e38f;
#pragma unroll
    for (int i = 0; i < S / 64; ++i) {
      int s = lane + 64 * i;
      vals[i] = s_sc[tr][s];
      if (s < len) m = fmaxf(m, vals[i]);
    }
#pragma unroll
    for (int o = 1; o < 64; o <<= 1) m = fmaxf(m, __shfl_xor(m, o, 64));
    float sum = 0.f;
#pragma unroll
    for (int i = 0; i < S / 64; ++i) {
      int s = lane + 64 * i;
      float p = (s < len) ? __builtin_amdgcn_exp2f((vals[i] - m) * 1.44269504088896341f) : 0.f;
      ps[i] = p;
      sum += p;
    }
#pragma unroll
    for (int o = 1; o < 64; o <<= 1) sum += __shfl_xor(sum, o, 64);
    float rs = 1.0f / sum;
#pragma unroll
    for (int i = 0; i < S / 64; ++i) s_sc[tr][lane + 64 * i] = ps[i];
    if (lane == 0) s_rs[tr] = rs;
    if (tt == T / TT - 1 && tr == TT - 1) {  // last timestep: attention weights
#pragma unroll
      for (int i = 0; i < S / 64; ++i)
        out[(size_t)B * T * H + (size_t)b * S + lane + 64 * i] = ps[i] * rs;
    }
  }
  __syncthreads();

  // ---- Phase C: ctx[t][h] = sum_{s<len} p[t][s] * enc[b][s][h]; wave = t ----
  {
    const int tg = tid >> 6, lane = tid & 63;
    const int h0 = lane * 4, h1 = 256 + lane * 4;
    float acc[8] = {};
    const float* encb = enc + (size_t)b * S * H;
#pragma unroll 2
    for (int s = 0; s < len; ++s) {
      float p = s_sc[tg][s];
      const float* er = encb + (size_t)s * H;
      float4 e0 = *(const float4*)(er + h0);
      float4 e1 = *(const float4*)(er + h1);
      float ev[8] = {e0.x, e0.y, e0.z, e0.w, e1.x, e1.y, e1.z, e1.w};
#pragma unroll
      for (int k = 0; k < 8; ++k) acc[k] = __builtin_fmaf(p, ev[k], acc[k]);
    }
    const float rs = s_rs[tg];
    const size_t base = ((size_t)b * T + tt * TT + tg) * H;
    float4 o;
    o = make_float4(acc[0] * rs, acc[1] * rs, acc[2] * rs, acc[3] * rs);
    *(float4*)&out[base + h0] = o;
    o = make_float4(acc[4] * rs, acc[5] * rs, acc[6] * rs, acc[7] * rs);
    *(float4*)&out[base + h1] = o;
  }
}

extern "C" void kernel_launch(void* const* d_in, const int* in_sizes, int n_in,
                              void* d_out, int out_size, void* d_ws, size_t ws_size,
                              hipStream_t stream) {
  const float* query = (const float*)d_in[0];  // [B,T,H]
  const float* enc   = (const float*)d_in[1];  // [B,S,H]
  const int*   lens  = (const int*)d_in[2];    // [B]
  const float* Ws    = (const float*)d_in[3];  // [H,H]
  const float* Wh    = (const float*)d_in[4];  // [H,H]
  const float* v     = (const float*)d_in[5];  // [H]
  float* out = (float*)d_out;
  float* wsq  = (float*)d_ws;                  // [B,T,H] = Q
  float* wheT = wsq + (size_t)B * T * H;       // [B,H/4,S,4] = E4

  matmul_nt_kernel<false><<<dim3((B * T / 64) * 8), 256, 0, stream>>>(query, Ws, wsq, C2LOG2E, nullptr);
  matmul_nt_kernel<true><<<dim3((B * S / 64) * 8), 256, 0, stream>>>(enc, Wh, wheT, C2LOG2E, lens);
  attn_fused_kernel<<<dim3(B * (T / TT)), 256, 0, stream>>>(wsq, wheT, enc, v, lens, out);
}